// Round 16
// baseline (227.466 us; speedup 1.0000x reference)
//
#include <hip/hip_runtime.h>
#include <hip/hip_bf16.h>

// B=4, S=1024, D=1024, H=16, HD=64
#define SS 1024
#define DD 1024
#define HH 16
#define HDD 64

using f32x4  = __attribute__((ext_vector_type(4))) float;
using bf16x8 = __attribute__((ext_vector_type(8))) __bf16;
using bf16x4 = __attribute__((ext_vector_type(4))) __bf16;

__device__ __forceinline__ void gload_lds16(const void* g, void* l) {
  __builtin_amdgcn_global_load_lds((__attribute__((address_space(1))) void*)g,
                                   (__attribute__((address_space(3))) void*)l, 16, 0, 0);
}

// -------- convert f32 -> bf16 (x, Wq|Wk|Wv stacked, Wo) ------------------------
__global__ void convert_kernel(const float4* __restrict__ x, const float4* __restrict__ Wq,
                               const float4* __restrict__ Wk, const float4* __restrict__ Wv,
                               const float4* __restrict__ Wo,
                               bf16x4* __restrict__ xb, bf16x4* __restrict__ wqkvb,
                               bf16x4* __restrict__ wob) {
  int i = blockIdx.x * 256 + threadIdx.x;   // 2097152 vec4 total, exact grid
  float4 v; bf16x4* dst;
  if (i < 1048576)      { v = x[i];              dst = xb + i; }
  else if (i < 1310720) { v = Wq[i - 1048576];   dst = wqkvb + (i - 1048576); }
  else if (i < 1572864) { v = Wk[i - 1310720];   dst = wqkvb + 262144 + (i - 1310720); }
  else if (i < 1835008) { v = Wv[i - 1572864];   dst = wqkvb + 524288 + (i - 1572864); }
  else                  { v = Wo[i - 1835008];   dst = wob + (i - 1835008); }
  bf16x4 o;
  o[0] = (__bf16)v.x; o[1] = (__bf16)v.y; o[2] = (__bf16)v.z; o[3] = (__bf16)v.w;
  *dst = o;
}

// -------- prep: Wk_avg rows 3072+ of wqkv (metric = rope(x@Wk_avg^T + bk_avg)) --
__global__ void prep_kernel(const __bf16* __restrict__ wqkv, const float* __restrict__ bk,
                            __bf16* __restrict__ wkavg, float* __restrict__ bkavg) {
  int idx = blockIdx.x * 512 + threadIdx.x;   // 8192 = 64 d x 128 k-groups
  int d = idx >> 7, k8 = (idx & 127) * 8;
  float s[8] = {};
#pragma unroll
  for (int h = 0; h < 16; ++h) {
    bf16x8 v = *(const bf16x8*)(wqkv + (size_t)(1024 + h * 64 + d) * 1024 + k8);
#pragma unroll
    for (int j = 0; j < 8; ++j) s[j] += (float)v[j];
  }
  bf16x8 o;
#pragma unroll
  for (int j = 0; j < 8; ++j) o[j] = (__bf16)(s[j] * 0.0625f);
  *(bf16x8*)(wkavg + (size_t)d * 1024 + k8) = o;
  if (blockIdx.x == 0 && threadIdx.x < 64) {
    float b = 0.f;
#pragma unroll
    for (int h = 0; h < 16; ++h) b += bk[h * 64 + threadIdx.x];
    bkavg[threadIdx.x] = b * 0.0625f;
  }
}

// ------- QKV GEMM: 128x128 tile, BK=64, 2-phase, chunk-XOR swizzle (N=3200) ----
#define GEMM_STAGE(BUF, KK)                                                        \
  {                                                                                \
    char* Ab = smem + (BUF) * 32768;                                               \
    char* Bb = Ab + 16384;                                                         \
    _Pragma("unroll") for (int q = 0; q < 4; ++q) {                                \
      int idx = q * 256 + tid;                                                     \
      int row = idx >> 3, c = idx & 7;                                             \
      gload_lds16(A  + (size_t)(m0 + row) * 1024 + (KK) + ((c ^ (row & 7)) << 3),  \
                  Ab + q * 4096 + wid * 1024);                                     \
      gload_lds16(Bm + (size_t)(n0 + row) * 1024 + (KK) + ((c ^ (row & 7)) << 3),  \
                  Bb + q * 4096 + wid * 1024);                                     \
    }                                                                              \
  }

__global__ __launch_bounds__(256, 2)
void gemm_qkv(const __bf16* __restrict__ A, const __bf16* __restrict__ Bm, int N,
              const float* __restrict__ b0, const float* __restrict__ b1,
              const float* __restrict__ b2, const float* __restrict__ bavg,
              const int* __restrict__ pos_ids,
              __bf16* __restrict__ Qr, __bf16* __restrict__ Kr, __bf16* __restrict__ Vtg,
              float* __restrict__ metric) {
  __shared__ __align__(16) char smem[65536];     // 2 x (As 16K | Bs 16K); vt_s reuse
  const int tid = threadIdx.x;
  const int wid = tid >> 6, lane = tid & 63;
  const int g = lane >> 4, cl = lane & 15;
  const int ntn = N >> 7;
  const int tile = (blockIdx.x & 7) * ((int)gridDim.x >> 3) + (blockIdx.x >> 3);
  const int bm = tile / ntn, bn = tile % ntn;
  const int m0 = bm << 7, n0 = bn << 7;
  const int wr = (wid >> 1) << 6, wc = (wid & 1) << 6;
  const int swz = cl & 7;

  f32x4 acc[4][4] = {};

  GEMM_STAGE(0, 0);
  __syncthreads();
  int buf = 0;
  for (int t = 0; t < 16; ++t) {
    if (t + 1 < 16) GEMM_STAGE(buf ^ 1, (t + 1) * 64);
    const __bf16* Abuf = (const __bf16*)(smem + buf * 32768);
    const __bf16* Bbuf = Abuf + 8192;
#pragma unroll
    for (int s = 0; s < 2; ++s) {
      bf16x8 fa[4], fb[4];
#pragma unroll
      for (int i = 0; i < 4; ++i)
        fa[i] = *(const bf16x8*)(Abuf + (wr + i * 16 + cl) * 64 + (((s * 4 + g) ^ swz) << 3));
#pragma unroll
      for (int j = 0; j < 4; ++j)
        fb[j] = *(const bf16x8*)(Bbuf + (wc + j * 16 + cl) * 64 + (((s * 4 + g) ^ swz) << 3));
#pragma unroll
      for (int i = 0; i < 4; ++i)
#pragma unroll
        for (int j = 0; j < 4; ++j)
          acc[i][j] = __builtin_amdgcn_mfma_f32_16x16x32_bf16(fa[i], fb[j], acc[i][j], 0, 0, 0);
    }
    __syncthreads();
    buf ^= 1;
  }

  if (n0 >= 3072) {
    // ---- metric region (cols 3072-3135 = Wk_avg): RoPE + direct f32 store ----
    if (wc == 0) {
      float invf0 = exp2f(-0.4152410118609203f * (float)(cl));
      float invf1 = exp2f(-0.4152410118609203f * (float)(16 + cl));
#pragma unroll
      for (int i = 0; i < 4; ++i) {
#pragma unroll
        for (int r = 0; r < 4; ++r) {
          int row = m0 + wr + i * 16 + g * 4 + r;
          float pos = (float)pos_ids[row];
#pragma unroll
          for (int j = 0; j < 2; ++j) {
            int dlo = j * 16 + cl;
            float vlo = acc[i][j][r]     + bavg[dlo];
            float vhi = acc[i][j + 2][r] + bavg[dlo + 32];
            float th = pos * (j == 0 ? invf0 : invf1);
            float sn, cs;
            __sincosf(th, &sn, &cs);
            metric[(size_t)row * HDD + dlo]      = vlo * cs - vhi * sn;
            metric[(size_t)row * HDD + dlo + 32] = vhi * cs + vlo * sn;
          }
        }
      }
    }
  } else if (n0 >= 2048) {
    // ---- V region: bias + transpose through LDS -> Vtg[b][h][d][s] ----
    __bf16* vt_s = (__bf16*)smem;                 // [64][136]
    const int b_ = m0 >> 10, s0 = m0 & 1023;
    const int vbase = n0 - 2048;
#pragma unroll
    for (int phase = 0; phase < 2; ++phase) {
      __syncthreads();
      if ((wid & 1) == phase) {
#pragma unroll
        for (int j = 0; j < 4; ++j) {
          int d = j * 16 + cl;
          float bv = b2[vbase + wc + d];
#pragma unroll
          for (int i = 0; i < 4; ++i)
#pragma unroll
            for (int r = 0; r < 4; ++r)
              vt_s[d * 136 + wr + i * 16 + g * 4 + r] = (__bf16)(acc[i][j][r] + bv);
        }
      }
      __syncthreads();
      int hh = (vbase >> 6) + phase;
#pragma unroll
      for (int p = 0; p < 4; ++p) {
        int d = p * 16 + (tid >> 4), s8 = (tid & 15) * 8;
        bf16x8 v = *(const bf16x8*)(vt_s + d * 136 + s8);
        *(bf16x8*)(Vtg + ((size_t)(b_ * HH + hh) * HDD + d) * SS + s0 + s8) = v;
      }
    }
  } else {
    // ---- Q/K region: bias + RoPE + scatter (no atomics) ----
    const int cb = n0 + wc;
    const int region = cb >> 10;
    const int hcol = (cb & 1023) >> 6;
    const int cir = cb & 1023;
    const float* bias = region == 0 ? b0 : b1;
    __bf16* dst = region == 0 ? Qr : Kr;
    float invf0 = exp2f(-0.4152410118609203f * (float)(cl));
    float invf1 = exp2f(-0.4152410118609203f * (float)(16 + cl));
#pragma unroll
    for (int i = 0; i < 4; ++i) {
#pragma unroll
      for (int r = 0; r < 4; ++r) {
        int row = m0 + wr + i * 16 + g * 4 + r;
        int b_ = row >> 10, s = row & 1023;
        size_t ob = ((size_t)(b_ * HH + hcol) * SS + s) * HDD;
        float pos = (float)pos_ids[row];
#pragma unroll
        for (int j = 0; j < 2; ++j) {
          int dlo = j * 16 + cl;
          float vlo = acc[i][j][r]     + bias[cir + dlo];
          float vhi = acc[i][j + 2][r] + bias[cir + dlo + 32];
          float th = pos * (j == 0 ? invf0 : invf1);
          float sn, cs;
          __sincosf(th, &sn, &cs);
          float olo = vlo * cs - vhi * sn;
          float ohi = vhi * cs + vlo * sn;
          dst[ob + dlo]      = (__bf16)olo;
          dst[ob + dlo + 32] = (__bf16)ohi;
        }
      }
    }
  }
}

// ------- O-proj GEMM: 128x64 tile (512 blocks = 2/CU), BK=64, 2-phase ----------
__global__ __launch_bounds__(256, 2)
void gemm_oproj(const __bf16* __restrict__ A, const __bf16* __restrict__ Bm,
                const float* __restrict__ b0, float* __restrict__ Cout) {
  __shared__ __align__(16) char smem[49152];     // 2 x (A 16K | B 8K)
  const int tid = threadIdx.x;
  const int wid = tid >> 6, lane = tid & 63;
  const int g = lane >> 4, cl = lane & 15;
  const int tile = (blockIdx.x & 7) * 64 + (blockIdx.x >> 3);  // grid 512
  const int bm = tile >> 4, bn = tile & 15;
  const int m0 = bm << 7, n0 = bn << 6;
  const int wr = (wid >> 1) << 6, wc = (wid & 1) << 5;
  const int swz = cl & 7;

  f32x4 acc[4][2] = {};

#define OP_STAGE(BUF, KK)                                                          \
  {                                                                                \
    char* Ab = smem + (BUF) * 24576;                                               \
    char* Bb2 = Ab + 16384;                                                        \
    _Pragma("unroll") for (int q = 0; q < 4; ++q) {                                \
      int idx = q * 256 + tid;                                                     \
      int row = idx >> 3, c = idx & 7;                                             \
      gload_lds16(A + (size_t)(m0 + row) * 1024 + (KK) + ((c ^ (row & 7)) << 3),   \
                  Ab + q * 4096 + wid * 1024);                                     \
    }                                                                              \
    _Pragma("unroll") for (int q = 0; q < 2; ++q) {                                \
      int idx = q * 256 + tid;                                                     \
      int row = idx >> 3, c = idx & 7;                                             \
      gload_lds16(Bm + (size_t)(n0 + row) * 1024 + (KK) + ((c ^ (row & 7)) << 3),  \
                  Bb2 + q * 4096 + wid * 1024);                                    \
    }                                                                              \
  }

  OP_STAGE(0, 0);
  __syncthreads();
  int buf = 0;
  for (int t = 0; t < 16; ++t) {
    if (t + 1 < 16) OP_STAGE(buf ^ 1, (t + 1) * 64);
    const __bf16* Abuf = (const __bf16*)(smem + buf * 24576);
    const __bf16* Bbuf = (const __bf16*)(smem + buf * 24576 + 16384);
#pragma unroll
    for (int s = 0; s < 2; ++s) {
      bf16x8 fa[4], fb[2];
#pragma unroll
      for (int i = 0; i < 4; ++i)
        fa[i] = *(const bf16x8*)(Abuf + (wr + i * 16 + cl) * 64 + (((s * 4 + g) ^ swz) << 3));
#pragma unroll
      for (int j = 0; j < 2; ++j)
        fb[j] = *(const bf16x8*)(Bbuf + (wc + j * 16 + cl) * 64 + (((s * 4 + g) ^ swz) << 3));
#pragma unroll
      for (int i = 0; i < 4; ++i)
#pragma unroll
        for (int j = 0; j < 2; ++j)
          acc[i][j] = __builtin_amdgcn_mfma_f32_16x16x32_bf16(fa[i], fb[j], acc[i][j], 0, 0, 0);
    }
    __syncthreads();
    buf ^= 1;
  }

#pragma unroll
  for (int j = 0; j < 2; ++j) {
    int col = n0 + wc + j * 16 + cl;
    float bv = b0[col];
#pragma unroll
    for (int i = 0; i < 4; ++i)
#pragma unroll
      for (int r = 0; r < 4; ++r) {
        int row = m0 + wr + i * 16 + g * 4 + r;
        Cout[(size_t)row * 1024 + col] = acc[i][j][r] + bv;
      }
  }
}

// ---------------- flash attention: barrier-free, L2-direct K/V ------------------
// 256 thr / 64 q-rows / block, grid 1024 (64 bh x 16 qb) bh-major. NO
// __syncthreads, NO K/V LDS: K,V read direct (L2-resident; kb1 hits the same
// 128B line as kb0). Bias in registers. LDS = 5KB per-wave P window only.
#define ATTN_HALF_D(KOFF, BI)                                                      \
  {                                                                                \
    f32x4 sc[4];                                                                   \
    __builtin_amdgcn_s_setprio(1);                                                 \
    _Pragma("unroll") for (int kt = 0; kt < 4; ++kt) {                             \
      const __bf16* kp = Kb + (size_t)(kk + (KOFF) + kt * 16 + cl) * 64;           \
      bf16x8 kb0 = *(const bf16x8*)(kp + g * 8);                                   \
      bf16x8 kb1 = *(const bf16x8*)(kp + 32 + g * 8);                              \
      f32x4 z = {0.f, 0.f, 0.f, 0.f};                                              \
      z = __builtin_amdgcn_mfma_f32_16x16x32_bf16(kb0, aq0, z, 0, 0, 0);           \
      sc[kt] = __builtin_amdgcn_mfma_f32_16x16x32_bf16(kb1, aq1, z, 0, 0, 0);      \
    }                                                                              \
    __builtin_amdgcn_s_setprio(0);                                                 \
    _Pragma("unroll") for (int kt = 0; kt < 4; ++kt)                               \
      _Pragma("unroll") for (int r = 0; r < 4; ++r)                                \
        sc[kt][r] = sc[kt][r] * 0.125f + breg[(BI) + kt][r];                       \
    float mx = fmaxf(fmaxf(fmaxf(sc[0][0], sc[0][1]), fmaxf(sc[0][2], sc[0][3])),  \
                     fmaxf(fmaxf(sc[1][0], sc[1][1]), fmaxf(sc[1][2], sc[1][3]))); \
    mx = fmaxf(mx, fmaxf(fmaxf(fmaxf(sc[2][0], sc[2][1]), fmaxf(sc[2][2], sc[2][3])), \
                         fmaxf(fmaxf(sc[3][0], sc[3][1]), fmaxf(sc[3][2], sc[3][3])))); \
    mx = fmaxf(mx, __shfl_xor(mx, 16, 64));                                        \
    mx = fmaxf(mx, __shfl_xor(mx, 32, 64));                                        \
    if (!__all(mx <= m_l + 8.0f)) {                                                \
      float nm = fmaxf(m_l, mx);                                                   \
      float s_ = __expf(m_l - nm);                                                 \
      m_l = nm; l_l *= s_;                                                         \
      float sb0 = __shfl(s_, 4 * g + 0, 64), sb1 = __shfl(s_, 4 * g + 1, 64);      \
      float sb2 = __shfl(s_, 4 * g + 2, 64), sb3 = __shfl(s_, 4 * g + 3, 64);      \
      _Pragma("unroll") for (int dj = 0; dj < 4; ++dj) {                           \
        o[dj][0] *= sb0; o[dj][1] *= sb1; o[dj][2] *= sb2; o[dj][3] *= sb3;        \
      }                                                                            \
    }                                                                              \
    _Pragma("unroll") for (int kt = 0; kt < 4; ++kt)                               \
      _Pragma("unroll") for (int r = 0; r < 4; ++r)                                \
        sc[kt][r] = __expf(sc[kt][r] - m_l);                                       \
    float rs = ((sc[0][0] + sc[0][1]) + (sc[0][2] + sc[0][3]))                     \
             + ((sc[1][0] + sc[1][1]) + (sc[1][2] + sc[1][3]))                     \
             + ((sc[2][0] + sc[2][1]) + (sc[2][2] + sc[2][3]))                     \
             + ((sc[3][0] + sc[3][1]) + (sc[3][2] + sc[3][3]));                    \
    rs += __shfl_xor(rs, 16, 64);                                                  \
    rs += __shfl_xor(rs, 32, 64);                                                  \
    l_l += rs;                                                                     \
    _Pragma("unroll") for (int w = 0; w < 2; ++w) {                                \
      _Pragma("unroll") for (int k2 = 0; k2 < 2; ++k2) {                           \
        int kt = w * 2 + k2;                                                       \
        bf16x4 pk;                                                                 \
        pk[0] = (__bf16)sc[kt][0]; pk[1] = (__bf16)sc[kt][1];                      \
        pk[2] = (__bf16)sc[kt][2]; pk[3] = (__bf16)sc[kt][3];                      \
        *(bf16x4*)(Pw + cl * 40 + k2 * 16 + 4 * g) = pk;                           \
      }                                                                            \
      bf16x8 pa = *(const bf16x8*)(Pw + cl * 40 + g * 8);                          \
      __builtin_amdgcn_s_setprio(1);                                               \
      _Pragma("unroll") for (int dj = 0; dj < 4; ++dj) {                           \
        bf16x8 vb = *(const bf16x8*)(Vb + (size_t)(dj * 16 + cl) * SS + kk + (KOFF) + w * 32 + g * 8); \
        o[dj] = __builtin_amdgcn_mfma_f32_16x16x32_bf16(pa, vb, o[dj], 0, 0, 0);   \
      }                                                                            \
      __builtin_amdgcn_s_setprio(0);                                               \
    }                                                                              \
  }

__global__ __launch_bounds__(256, 4)
void attn_kernel(const __bf16* __restrict__ Qr, const __bf16* __restrict__ Kr,
                 const __bf16* __restrict__ Vtg, const float* __restrict__ bias,
                 const int* __restrict__ pad, __bf16* __restrict__ attn_out) {
  __shared__ __align__(16) __bf16 Plds[4][16][40]; // 5 KB per-wave P window
  const int tid = threadIdx.x;
  const int wid = tid >> 6, lane = tid & 63;
  const int g = lane >> 4, cl = lane & 15;
  const int bh = blockIdx.x & 63, b_ = bh >> 4, h = bh & 15;   // bh-major: XCD = bh%8
  const int q0 = (blockIdx.x >> 6) * 64 + wid * 16;            // qb in 0..15 -> q0 <= 1008
  const __bf16* Qb = Qr  + ((size_t)bh << 16);
  const __bf16* Kb = Kr  + ((size_t)bh << 16);
  const __bf16* Vb = Vtg + ((size_t)bh << 16);
  const float*  Bb = bias + ((size_t)bh << 20);
  const int* padb = pad + b_ * SS;

  int pm = (lane < 16) ? padb[lane * 64] : 1;
  unsigned long long ball = __ballot(pm == 0);
  const int valid64 = __popcll(ball & 0xFFFFull);
  const int nt = (valid64 + 1) >> 1;
  const int tail = valid64 & 1;

  __bf16* Pw = &Plds[wid][0][0];

  bf16x8 aq0 = *(const bf16x8*)(Qb + (size_t)(q0 + cl) * 64 + g * 8);
  bf16x8 aq1 = *(const bf16x8*)(Qb + (size_t)(q0 + cl) * 64 + 32 + g * 8);

  f32x4 o[4] = {};
  float m_l = -1e30f, l_l = 0.f;

  for (int t = 0; t < nt; ++t) {
    const int kk = t * 128;
    f32x4 breg[8];
#pragma unroll
    for (int kt = 0; kt < 8; ++kt)
      breg[kt] = *(const f32x4*)(Bb + (size_t)(q0 + cl) * SS + kk + kt * 16 + 4 * g);

    ATTN_HALF_D(0, 0);
    if (!(tail && t == nt - 1))
      ATTN_HALF_D(64, 4);
  }

  float lb0 = __shfl(l_l, 4 * g + 0, 64), lb1 = __shfl(l_l, 4 * g + 1, 64);
  float lb2 = __shfl(l_l, 4 * g + 2, 64), lb3 = __shfl(l_l, 4 * g + 3, 64);
  float ib0 = 1.f / lb0, ib1 = 1.f / lb1, ib2 = 1.f / lb2, ib3 = 1.f / lb3;
#pragma unroll
  for (int dj = 0; dj < 4; ++dj) {
    int col = h * 64 + dj * 16 + cl;
    attn_out[(size_t)(b_ * SS + q0 + g * 4 + 0) * DD + col] = (__bf16)(o[dj][0] * ib0);
    attn_out[(size_t)(b_ * SS + q0 + g * 4 + 1) * DD + col] = (__bf16)(o[dj][1] * ib1);
    attn_out[(size_t)(b_ * SS + q0 + g * 4 + 2) * DD + col] = (__bf16)(o[dj][2] * ib2);
    attn_out[(size_t)(b_ * SS + q0 + g * 4 + 3) * DD + col] = (__bf16)(o[dj][3] * ib3);
  }
}

// ------------------------------- launcher --------------------------------------
extern "C" void kernel_launch(void* const* d_in, const int* in_sizes, int n_in,
                              void* d_out, int out_size, void* d_ws, size_t ws_size,
                              hipStream_t stream) {
  const float* x  = (const float*)d_in[0];
  const float* ab = (const float*)d_in[1];
  const int* pos  = (const int*)d_in[2];
  const int* pad  = (const int*)d_in[3];
  const float* Wq = (const float*)d_in[4];
  const float* bq = (const float*)d_in[5];
  const float* Wk = (const float*)d_in[6];
  const float* bk = (const float*)d_in[7];
  const float* Wv = (const float*)d_in[8];
  const float* bv = (const float*)d_in[9];
  const float* Wo = (const float*)d_in[10];
  const float* bo = (const float*)d_in[11];
  float* out = (float*)d_out;
  float* metric = out + 4194304;           // [B,S,64] f32

  char* ws = (char*)d_ws;
  __bf16* Qr    = (__bf16*)(ws);                 // [B,H,S,64] bf16, 8 MB
  __bf16* Kr    = (__bf16*)(ws + 8388608);       // [B,H,S,64]
  __bf16* Vtg   = (__bf16*)(ws + 16777216);      // [B,H,64,S]  (pre-transposed V)
  __bf16* xb    = (__bf16*)(ws + 25165824);      // [4096,1024] bf16
  __bf16* wqkv  = (__bf16*)(ws + 33554432);      // [3200,1024] bf16 (rows 3072+ = Wk_avg)
  __bf16* wob   = (__bf16*)(ws + 40108032);      // [1024,1024] bf16
  __bf16* ao    = (__bf16*)(ws + 42205184);      // attn out [4096,1024] bf16
  float*  bkavg = (float*)(ws + 50593792);       // [64] f32

  convert_kernel<<<8192, 256, 0, stream>>>((const float4*)x, (const float4*)Wq,
                                           (const float4*)Wk, (const float4*)Wv,
                                           (const float4*)Wo, (bf16x4*)xb,
                                           (bf16x4*)wqkv, (bf16x4*)wob);
  prep_kernel<<<16, 512, 0, stream>>>(wqkv, bk, wqkv + (size_t)3072 * 1024, bkavg);
  gemm_qkv<<<800, 256, 0, stream>>>(xb, wqkv, 3200, bq, bk, bv, bkavg, pos,
                                    Qr, Kr, Vtg, metric);
  attn_kernel<<<1024, 256, 0, stream>>>(Qr, Kr, Vtg, ab, pad, ao);
  gemm_oproj<<<512, 256, 0, stream>>>(ao, wob, bo, out);
}

// Round 18
// 147.658 us; speedup vs baseline: 1.5405x; 1.5405x over previous
//
#include <hip/hip_runtime.h>
#include <hip/hip_bf16.h>

// B=4, S=1024, D=1024, H=16, HD=64
#define SS 1024
#define DD 1024
#define HH 16
#define HDD 64

using f32x4  = __attribute__((ext_vector_type(4))) float;
using bf16x8 = __attribute__((ext_vector_type(8))) __bf16;
using bf16x4 = __attribute__((ext_vector_type(4))) __bf16;

__device__ __forceinline__ void gload_lds16(const void* g, void* l) {
  __builtin_amdgcn_global_load_lds((__attribute__((address_space(1))) void*)g,
                                   (__attribute__((address_space(3))) void*)l, 16, 0, 0);
}

// -------- convert f32 -> bf16 (x, Wq|Wk|Wv stacked, Wo) ------------------------
__global__ void convert_kernel(const float4* __restrict__ x, const float4* __restrict__ Wq,
                               const float4* __restrict__ Wk, const float4* __restrict__ Wv,
                               const float4* __restrict__ Wo,
                               bf16x4* __restrict__ xb, bf16x4* __restrict__ wqkvb,
                               bf16x4* __restrict__ wob) {
  int i = blockIdx.x * 256 + threadIdx.x;   // 2097152 vec4 total, exact grid
  float4 v; bf16x4* dst;
  if (i < 1048576)      { v = x[i];              dst = xb + i; }
  else if (i < 1310720) { v = Wq[i - 1048576];   dst = wqkvb + (i - 1048576); }
  else if (i < 1572864) { v = Wk[i - 1310720];   dst = wqkvb + 262144 + (i - 1310720); }
  else if (i < 1835008) { v = Wv[i - 1572864];   dst = wqkvb + 524288 + (i - 1572864); }
  else                  { v = Wo[i - 1835008];   dst = wob + (i - 1835008); }
  bf16x4 o;
  o[0] = (__bf16)v.x; o[1] = (__bf16)v.y; o[2] = (__bf16)v.z; o[3] = (__bf16)v.w;
  *dst = o;
}

// -------- prep: Wk_avg rows 3072+ of wqkv (metric = rope(x@Wk_avg^T + bk_avg)) --
__global__ void prep_kernel(const __bf16* __restrict__ wqkv, const float* __restrict__ bk,
                            __bf16* __restrict__ wkavg, float* __restrict__ bkavg) {
  int idx = blockIdx.x * 512 + threadIdx.x;   // 8192 = 64 d x 128 k-groups
  int d = idx >> 7, k8 = (idx & 127) * 8;
  float s[8] = {};
#pragma unroll
  for (int h = 0; h < 16; ++h) {
    bf16x8 v = *(const bf16x8*)(wqkv + (size_t)(1024 + h * 64 + d) * 1024 + k8);
#pragma unroll
    for (int j = 0; j < 8; ++j) s[j] += (float)v[j];
  }
  bf16x8 o;
#pragma unroll
  for (int j = 0; j < 8; ++j) o[j] = (__bf16)(s[j] * 0.0625f);
  *(bf16x8*)(wkavg + (size_t)d * 1024 + k8) = o;
  if (blockIdx.x == 0 && threadIdx.x < 64) {
    float b = 0.f;
#pragma unroll
    for (int h = 0; h < 16; ++h) b += bk[h * 64 + threadIdx.x];
    bkavg[threadIdx.x] = b * 0.0625f;
  }
}

// ------- GEMM: C[M,N] = A[M,1024] * Bm[N,1024]^T (NT, bf16 MFMA) ---------------
// 128x128 tile, BK=64, double-buffered LDS, 2-phase pipeline, chunk-XOR swizzle.
// EPI==0: N=3200. Regions: Q (RoPE), K (RoPE), V (transpose), metric (RoPE+f32).
// EPI==1: O-proj epilogue (bias + f32 store)
#define GEMM_STAGE(BUF, KK)                                                        \
  {                                                                                \
    char* Ab = smem + (BUF) * 32768;                                               \
    char* Bb = Ab + 16384;                                                         \
    _Pragma("unroll") for (int q = 0; q < 4; ++q) {                                \
      int idx = q * 256 + tid;                                                     \
      int row = idx >> 3, c = idx & 7;                                             \
      gload_lds16(A  + (size_t)(m0 + row) * 1024 + (KK) + ((c ^ (row & 7)) << 3),  \
                  Ab + q * 4096 + wid * 1024);                                     \
      gload_lds16(Bm + (size_t)(n0 + row) * 1024 + (KK) + ((c ^ (row & 7)) << 3),  \
                  Bb + q * 4096 + wid * 1024);                                     \
    }                                                                              \
  }

template<int EPI>
__global__ __launch_bounds__(256, 2)
void gemm_kernel(const __bf16* __restrict__ A, const __bf16* __restrict__ Bm, int N,
                 const float* __restrict__ b0, const float* __restrict__ b1,
                 const float* __restrict__ b2, const float* __restrict__ bavg,
                 const int* __restrict__ pos_ids,
                 __bf16* __restrict__ Qr, __bf16* __restrict__ Kr, __bf16* __restrict__ Vtg,
                 float* __restrict__ metric, float* __restrict__ Cout) {
  __shared__ __align__(16) char smem[65536];     // 2 x (As 16K | Bs 16K); vt_s reuse
  const int tid = threadIdx.x;
  const int wid = tid >> 6, lane = tid & 63;
  const int g = lane >> 4, cl = lane & 15;
  const int ntn = N >> 7;
  const int tile = (blockIdx.x & 7) * ((int)gridDim.x >> 3) + (blockIdx.x >> 3);
  const int bm = tile / ntn, bn = tile % ntn;
  const int m0 = bm << 7, n0 = bn << 7;
  const int wr = (wid >> 1) << 6, wc = (wid & 1) << 6;
  const int swz = cl & 7;

  f32x4 acc[4][4] = {};

  GEMM_STAGE(0, 0);
  __syncthreads();                                // tile-0 landed
  int buf = 0;
  for (int t = 0; t < 16; ++t) {
    if (t + 1 < 16) GEMM_STAGE(buf ^ 1, (t + 1) * 64);   // prefetch next K-step
    const __bf16* Abuf = (const __bf16*)(smem + buf * 32768);
    const __bf16* Bbuf = Abuf + 8192;
#pragma unroll
    for (int s = 0; s < 2; ++s) {                 // two K=32 substeps
      bf16x8 fa[4], fb[4];
#pragma unroll
      for (int i = 0; i < 4; ++i)
        fa[i] = *(const bf16x8*)(Abuf + (wr + i * 16 + cl) * 64 + (((s * 4 + g) ^ swz) << 3));
#pragma unroll
      for (int j = 0; j < 4; ++j)
        fb[j] = *(const bf16x8*)(Bbuf + (wc + j * 16 + cl) * 64 + (((s * 4 + g) ^ swz) << 3));
#pragma unroll
      for (int i = 0; i < 4; ++i)
#pragma unroll
        for (int j = 0; j < 4; ++j)
          acc[i][j] = __builtin_amdgcn_mfma_f32_16x16x32_bf16(fa[i], fb[j], acc[i][j], 0, 0, 0);
    }
    __syncthreads();                              // drains prefetch (full compute cover)
    buf ^= 1;
  }

  if constexpr (EPI == 1) {
#pragma unroll
    for (int j = 0; j < 4; ++j) {
      int col = n0 + wc + j * 16 + cl;
      float bv = b0[col];
#pragma unroll
      for (int i = 0; i < 4; ++i)
#pragma unroll
        for (int r = 0; r < 4; ++r) {
          int row = m0 + wr + i * 16 + g * 4 + r;
          Cout[(size_t)row * 1024 + col] = acc[i][j][r] + bv;
        }
    }
  } else if (n0 >= 3072) {
    // ---- metric region (cols 3072-3135 = Wk_avg): RoPE + direct f32 store ----
    if (wc == 0) {
      float invf0 = exp2f(-0.4152410118609203f * (float)(cl));
      float invf1 = exp2f(-0.4152410118609203f * (float)(16 + cl));
#pragma unroll
      for (int i = 0; i < 4; ++i) {
#pragma unroll
        for (int r = 0; r < 4; ++r) {
          int row = m0 + wr + i * 16 + g * 4 + r;
          float pos = (float)pos_ids[row];
#pragma unroll
          for (int j = 0; j < 2; ++j) {
            int dlo = j * 16 + cl;
            float vlo = acc[i][j][r]     + bavg[dlo];
            float vhi = acc[i][j + 2][r] + bavg[dlo + 32];
            float th = pos * (j == 0 ? invf0 : invf1);
            float sn, cs;
            __sincosf(th, &sn, &cs);
            metric[(size_t)row * HDD + dlo]      = vlo * cs - vhi * sn;
            metric[(size_t)row * HDD + dlo + 32] = vhi * cs + vlo * sn;
          }
        }
      }
    }
  } else if (n0 >= 2048) {
    // ---- V region: bias + transpose through LDS -> Vtg[b][h][d][s] ----
    __bf16* vt_s = (__bf16*)smem;                 // [64][136]
    const int b_ = m0 >> 10, s0 = m0 & 1023;
    const int vbase = n0 - 2048;
#pragma unroll
    for (int phase = 0; phase < 2; ++phase) {
      __syncthreads();
      if ((wid & 1) == phase) {
#pragma unroll
        for (int j = 0; j < 4; ++j) {
          int d = j * 16 + cl;
          float bv = b2[vbase + wc + d];
#pragma unroll
          for (int i = 0; i < 4; ++i)
#pragma unroll
            for (int r = 0; r < 4; ++r)
              vt_s[d * 136 + wr + i * 16 + g * 4 + r] = (__bf16)(acc[i][j][r] + bv);
        }
      }
      __syncthreads();
      int hh = (vbase >> 6) + phase;
#pragma unroll
      for (int p = 0; p < 4; ++p) {
        int d = p * 16 + (tid >> 4), s8 = (tid & 15) * 8;
        bf16x8 v = *(const bf16x8*)(vt_s + d * 136 + s8);
        *(bf16x8*)(Vtg + ((size_t)(b_ * HH + hh) * HDD + d) * SS + s0 + s8) = v;
      }
    }
  } else {
    // ---- Q/K region: bias + RoPE + scatter (no atomics) ----
    const int cb = n0 + wc;
    const int region = cb >> 10;
    const int hcol = (cb & 1023) >> 6;
    const int cir = cb & 1023;
    const float* bias = region == 0 ? b0 : b1;
    __bf16* dst = region == 0 ? Qr : Kr;
    float invf0 = exp2f(-0.4152410118609203f * (float)(cl));
    float invf1 = exp2f(-0.4152410118609203f * (float)(16 + cl));
#pragma unroll
    for (int i = 0; i < 4; ++i) {
#pragma unroll
      for (int r = 0; r < 4; ++r) {
        int row = m0 + wr + i * 16 + g * 4 + r;
        int b_ = row >> 10, s = row & 1023;
        size_t ob = ((size_t)(b_ * HH + hcol) * SS + s) * HDD;
        float pos = (float)pos_ids[row];
#pragma unroll
        for (int j = 0; j < 2; ++j) {
          int dlo = j * 16 + cl;
          float vlo = acc[i][j][r]     + bias[cir + dlo];
          float vhi = acc[i][j + 2][r] + bias[cir + dlo + 32];
          float th = pos * (j == 0 ? invf0 : invf1);
          float sn, cs;
          __sincosf(th, &sn, &cs);
          float olo = vlo * cs - vhi * sn;
          float ohi = vhi * cs + vlo * sn;
          dst[ob + dlo]      = (__bf16)olo;
          dst[ob + dlo + 32] = (__bf16)ohi;
        }
      }
    }
  }
}

// ---------------- flash attention: KBLK=128, plain-barrier pipeline -------------
// (R14 structure with __syncthreads() tile top — counted-vmcnt proved perf-
//  neutral in R11/R12 A/B, so use the simpler, race-proof barrier.)
#define ATTN_HALF(KT0, W0, BCUR)                                                   \
  {                                                                                \
    f32x4 sc[4];                                                                   \
    __builtin_amdgcn_s_setprio(1);                                                 \
    _Pragma("unroll") for (int kt = 0; kt < 4; ++kt) {                             \
      int row = (KT0 + kt) * 16 + cl;                                              \
      bf16x8 kb0 = *(const bf16x8*)(&Ks[buf][row][(g ^ swz) * 8]);                 \
      bf16x8 kb1 = *(const bf16x8*)(&Ks[buf][row][((g + 4) ^ swz) * 8]);           \
      f32x4 z = {0.f, 0.f, 0.f, 0.f};                                              \
      z = __builtin_amdgcn_mfma_f32_16x16x32_bf16(kb0, aq0, z, 0, 0, 0);           \
      sc[kt] = __builtin_amdgcn_mfma_f32_16x16x32_bf16(kb1, aq1, z, 0, 0, 0);      \
    }                                                                              \
    __builtin_amdgcn_s_setprio(0);                                                 \
    _Pragma("unroll") for (int kt = 0; kt < 4; ++kt)                               \
      _Pragma("unroll") for (int r = 0; r < 4; ++r)                                \
        sc[kt][r] = sc[kt][r] * 0.125f + BCUR[KT0 + kt][r];                        \
    float mx = fmaxf(fmaxf(fmaxf(sc[0][0], sc[0][1]), fmaxf(sc[0][2], sc[0][3])),  \
                     fmaxf(fmaxf(sc[1][0], sc[1][1]), fmaxf(sc[1][2], sc[1][3]))); \
    mx = fmaxf(mx, fmaxf(fmaxf(fmaxf(sc[2][0], sc[2][1]), fmaxf(sc[2][2], sc[2][3])), \
                         fmaxf(fmaxf(sc[3][0], sc[3][1]), fmaxf(sc[3][2], sc[3][3])))); \
    mx = fmaxf(mx, __shfl_xor(mx, 16, 64));                                        \
    mx = fmaxf(mx, __shfl_xor(mx, 32, 64));                                        \
    if (!__all(mx <= m_l + 8.0f)) {                                                \
      float nm = fmaxf(m_l, mx);                                                   \
      float s_ = __expf(m_l - nm);                                                 \
      m_l = nm; l_l *= s_;                                                         \
      float sb0 = __shfl(s_, 4 * g + 0, 64), sb1 = __shfl(s_, 4 * g + 1, 64);      \
      float sb2 = __shfl(s_, 4 * g + 2, 64), sb3 = __shfl(s_, 4 * g + 3, 64);      \
      _Pragma("unroll") for (int dj = 0; dj < 4; ++dj) {                           \
        o[dj][0] *= sb0; o[dj][1] *= sb1; o[dj][2] *= sb2; o[dj][3] *= sb3;        \
      }                                                                            \
    }                                                                              \
    _Pragma("unroll") for (int kt = 0; kt < 4; ++kt)                               \
      _Pragma("unroll") for (int r = 0; r < 4; ++r)                                \
        sc[kt][r] = __expf(sc[kt][r] - m_l);                                       \
    float rs = ((sc[0][0] + sc[0][1]) + (sc[0][2] + sc[0][3]))                     \
             + ((sc[1][0] + sc[1][1]) + (sc[1][2] + sc[1][3]))                     \
             + ((sc[2][0] + sc[2][1]) + (sc[2][2] + sc[2][3]))                     \
             + ((sc[3][0] + sc[3][1]) + (sc[3][2] + sc[3][3]));                    \
    rs += __shfl_xor(rs, 16, 64);                                                  \
    rs += __shfl_xor(rs, 32, 64);                                                  \
    l_l += rs;                                                                     \
    _Pragma("unroll") for (int w = 0; w < 2; ++w) {                                \
      _Pragma("unroll") for (int k2 = 0; k2 < 2; ++k2) {                           \
        int kt = w * 2 + k2;                                                       \
        bf16x4 pk;                                                                 \
        pk[0] = (__bf16)sc[kt][0]; pk[1] = (__bf16)sc[kt][1];                      \
        pk[2] = (__bf16)sc[kt][2]; pk[3] = (__bf16)sc[kt][3];                      \
        *(bf16x4*)(Pw + cl * 40 + k2 * 16 + 4 * g) = pk;                           \
      }                                                                            \
      bf16x8 pa = *(const bf16x8*)(Pw + cl * 40 + g * 8);                          \
      __builtin_amdgcn_s_setprio(1);                                               \
      _Pragma("unroll") for (int dj = 0; dj < 4; ++dj) {                           \
        int vrow = dj * 16 + cl;                                                   \
        bf16x8 vb = *(const bf16x8*)(&Vt[buf][vrow][((((W0 + w) * 4) + g) ^ swz) * 8]); \
        o[dj] = __builtin_amdgcn_mfma_f32_16x16x32_bf16(pa, vb, o[dj], 0, 0, 0);   \
      }                                                                            \
      __builtin_amdgcn_s_setprio(0);                                               \
    }                                                                              \
  }

#define ATTN_STAGE(NB, KK)                                                         \
  _Pragma("unroll") for (int s = 0; s < 2; ++s) {                                  \
    gload_lds16(Kb + (size_t)((KK) + s * 64 + krow) * 64 + kchk * 8,               \
                (char*)&Ks[NB][s * 64 + 8 * wid][0]);                              \
    gload_lds16(Vb + (size_t)(s * 32 + vrow) * SS + (KK) + vchk * 8,               \
                (char*)&Vt[NB][s * 32 + 4 * wid][0]);                              \
  }

__global__ __launch_bounds__(512, 4)
void attn_kernel(const __bf16* __restrict__ Qr, const __bf16* __restrict__ Kr,
                 const __bf16* __restrict__ Vtg, const float* __restrict__ bias,
                 const int* __restrict__ pad, __bf16* __restrict__ attn_out) {
  __shared__ __align__(16) __bf16 Ks[2][128][64];  // 32 KB [buf][k][d] swizzled
  __shared__ __align__(16) __bf16 Vt[2][64][128];  // 32 KB [buf][d][k] swizzled
  __shared__ __align__(16) __bf16 Plds[8][16][40]; // 10 KB per-wave P window
  const int tid = threadIdx.x;
  const int wid = tid >> 6, lane = tid & 63;
  const int g = lane >> 4, cl = lane & 15;
  const int bh = blockIdx.x & 63, b_ = bh >> 4, h = bh & 15;   // bh-major: XCD = bh%8
  const int q0 = (blockIdx.x >> 6) * 128 + wid * 16;
  const __bf16* Qb = Qr  + ((size_t)bh << 16);
  const __bf16* Kb = Kr  + ((size_t)bh << 16);
  const __bf16* Vb = Vtg + ((size_t)bh << 16);
  const float*  Bb = bias + ((size_t)bh << 20);
  const int* padb = pad + b_ * SS;

  int pm = (lane < 16) ? padb[lane * 64] : 1;
  unsigned long long ball = __ballot(pm == 0);
  const int valid64 = __popcll(ball & 0xFFFFull);
  const int nt = (valid64 + 1) >> 1;
  const int tail = valid64 & 1;

  const int krow = 8 * wid + (lane >> 3);
  const int kchk = (lane & 7) ^ (lane >> 3);
  const int vrow = 4 * wid + (lane >> 4);
  const int vchk = (lane & 15) ^ (vrow & 7);
  const int swz = cl & 7;
  __bf16* Pw = &Plds[wid][0][0];

  bf16x8 aq0 = *(const bf16x8*)(Qb + (size_t)(q0 + cl) * 64 + g * 8);
  bf16x8 aq1 = *(const bf16x8*)(Qb + (size_t)(q0 + cl) * 64 + 32 + g * 8);

  ATTN_STAGE(0, 0);
  f32x4 breg[8];
#pragma unroll
  for (int kt = 0; kt < 8; ++kt)
    breg[kt] = *(const f32x4*)(Bb + (size_t)(q0 + cl) * SS + kt * 16 + 4 * g);

  f32x4 o[4] = {};
  float m_l = -1e30f, l_l = 0.f;

  for (int t = 0; t < nt; ++t) {
    const int buf = t & 1;
    __syncthreads();                    // tile-t staging landed; buf^1 free
    if (t + 1 < nt) ATTN_STAGE(buf ^ 1, (t + 1) * 128);

    ATTN_HALF(0, 0, breg);

    if (t + 1 < nt) {                   // reload bias-lo under HALF1's compute
      int kk2 = (t + 1) * 128;
#pragma unroll
      for (int kt = 0; kt < 4; ++kt)
        breg[kt] = *(const f32x4*)(Bb + (size_t)(q0 + cl) * SS + kk2 + kt * 16 + 4 * g);
    }

    if (!(tail && t == nt - 1))
      ATTN_HALF(4, 2, breg);

    if (t + 1 < nt) {
      int kk2 = (t + 1) * 128;
#pragma unroll
      for (int kt = 4; kt < 8; ++kt)
        breg[kt] = *(const f32x4*)(Bb + (size_t)(q0 + cl) * SS + kk2 + kt * 16 + 4 * g);
    }
  }

  float lb0 = __shfl(l_l, 4 * g + 0, 64), lb1 = __shfl(l_l, 4 * g + 1, 64);
  float lb2 = __shfl(l_l, 4 * g + 2, 64), lb3 = __shfl(l_l, 4 * g + 3, 64);
  float ib0 = 1.f / lb0, ib1 = 1.f / lb1, ib2 = 1.f / lb2, ib3 = 1.f / lb3;
#pragma unroll
  for (int dj = 0; dj < 4; ++dj) {
    int col = h * 64 + dj * 16 + cl;
    attn_out[(size_t)(b_ * SS + q0 + g * 4 + 0) * DD + col] = (__bf16)(o[dj][0] * ib0);
    attn_out[(size_t)(b_ * SS + q0 + g * 4 + 1) * DD + col] = (__bf16)(o[dj][1] * ib1);
    attn_out[(size_t)(b_ * SS + q0 + g * 4 + 2) * DD + col] = (__bf16)(o[dj][2] * ib2);
    attn_out[(size_t)(b_ * SS + q0 + g * 4 + 3) * DD + col] = (__bf16)(o[dj][3] * ib3);
  }
}

// ------------------------------- launcher --------------------------------------
extern "C" void kernel_launch(void* const* d_in, const int* in_sizes, int n_in,
                              void* d_out, int out_size, void* d_ws, size_t ws_size,
                              hipStream_t stream) {
  const float* x  = (const float*)d_in[0];
  const float* ab = (const float*)d_in[1];
  const int* pos  = (const int*)d_in[2];
  const int* pad  = (const int*)d_in[3];
  const float* Wq = (const float*)d_in[4];
  const float* bq = (const float*)d_in[5];
  const float* Wk = (const float*)d_in[6];
  const float* bk = (const float*)d_in[7];
  const float* Wv = (const float*)d_in[8];
  const float* bv = (const float*)d_in[9];
  const float* Wo = (const float*)d_in[10];
  const float* bo = (const float*)d_in[11];
  float* out = (float*)d_out;
  float* metric = out + 4194304;           // [B,S,64] f32

  char* ws = (char*)d_ws;
  __bf16* Qr    = (__bf16*)(ws);                 // [B,H,S,64] bf16, 8 MB
  __bf16* Kr    = (__bf16*)(ws + 8388608);       // [B,H,S,64]
  __bf16* Vtg   = (__bf16*)(ws + 16777216);      // [B,H,64,S]  (pre-transposed V)
  __bf16* xb    = (__bf16*)(ws + 25165824);      // [4096,1024] bf16
  __bf16* wqkv  = (__bf16*)(ws + 33554432);      // [3200,1024] bf16 (rows 3072+ = Wk_avg)
  __bf16* wob   = (__bf16*)(ws + 40108032);      // [1024,1024] bf16
  __bf16* ao    = (__bf16*)(ws + 42205184);      // attn out [4096,1024] bf16
  float*  bkavg = (float*)(ws + 50593792);       // [64] f32

  convert_kernel<<<8192, 256, 0, stream>>>((const float4*)x, (const float4*)Wq,
                                           (const float4*)Wk, (const float4*)Wv,
                                           (const float4*)Wo, (bf16x4*)xb,
                                           (bf16x4*)wqkv, (bf16x4*)wob);
  prep_kernel<<<16, 512, 0, stream>>>(wqkv, bk, wqkv + (size_t)3072 * 1024, bkavg);
  gemm_kernel<0><<<800, 256, 0, stream>>>(xb, wqkv, 3200, bq, bk, bv, bkavg, pos,
                                          Qr, Kr, Vtg, metric, nullptr);
  attn_kernel<<<512, 512, 0, stream>>>(Qr, Kr, Vtg, ab, pad, ao);
  gemm_kernel<1><<<256, 256, 0, stream>>>(ao, wob, 1024, bo, nullptr, nullptr, nullptr,
                                          nullptr, nullptr, nullptr, nullptr, nullptr, out);
}

// Round 19
// 143.664 us; speedup vs baseline: 1.5833x; 1.0278x over previous
//
#include <hip/hip_runtime.h>
#include <hip/hip_bf16.h>

// B=4, S=1024, D=1024, H=16, HD=64
#define SS 1024
#define DD 1024
#define HH 16
#define HDD 64

using f32x4  = __attribute__((ext_vector_type(4))) float;
using bf16x8 = __attribute__((ext_vector_type(8))) __bf16;
using bf16x4 = __attribute__((ext_vector_type(4))) __bf16;

__device__ __forceinline__ void gload_lds16(const void* g, void* l) {
  __builtin_amdgcn_global_load_lds((__attribute__((address_space(1))) void*)g,
                                   (__attribute__((address_space(3))) void*)l, 16, 0, 0);
}

// -------- convert f32 -> bf16 (x, Wq|Wk|Wv stacked, Wo) ------------------------
__global__ void convert_kernel(const float4* __restrict__ x, const float4* __restrict__ Wq,
                               const float4* __restrict__ Wk, const float4* __restrict__ Wv,
                               const float4* __restrict__ Wo,
                               bf16x4* __restrict__ xb, bf16x4* __restrict__ wqkvb,
                               bf16x4* __restrict__ wob) {
  int i = blockIdx.x * 256 + threadIdx.x;   // 2097152 vec4 total, exact grid
  float4 v; bf16x4* dst;
  if (i < 1048576)      { v = x[i];              dst = xb + i; }
  else if (i < 1310720) { v = Wq[i - 1048576];   dst = wqkvb + (i - 1048576); }
  else if (i < 1572864) { v = Wk[i - 1310720];   dst = wqkvb + 262144 + (i - 1310720); }
  else if (i < 1835008) { v = Wv[i - 1572864];   dst = wqkvb + 524288 + (i - 1572864); }
  else                  { v = Wo[i - 1835008];   dst = wob + (i - 1835008); }
  bf16x4 o;
  o[0] = (__bf16)v.x; o[1] = (__bf16)v.y; o[2] = (__bf16)v.z; o[3] = (__bf16)v.w;
  *dst = o;
}

// -------- prep: Wk_avg[d,k] = mean_h Wk[h*64+d, k] (bf16, into wqkv rows 3072+),
//          bk_avg[d] = mean_h bk[h*64+d] (f32). metric = rope(x@Wk_avg^T + bk_avg)
//          replaces 4.2M epilogue atomics (metric is linear in heads).
__global__ void prep_kernel(const __bf16* __restrict__ wqkv, const float* __restrict__ bk,
                            __bf16* __restrict__ wkavg, float* __restrict__ bkavg) {
  int idx = blockIdx.x * 512 + threadIdx.x;   // 8192 = 64 d x 128 k-groups
  int d = idx >> 7, k8 = (idx & 127) * 8;
  float s[8] = {};
#pragma unroll
  for (int h = 0; h < 16; ++h) {
    bf16x8 v = *(const bf16x8*)(wqkv + (size_t)(1024 + h * 64 + d) * 1024 + k8);
#pragma unroll
    for (int j = 0; j < 8; ++j) s[j] += (float)v[j];
  }
  bf16x8 o;
#pragma unroll
  for (int j = 0; j < 8; ++j) o[j] = (__bf16)(s[j] * 0.0625f);
  *(bf16x8*)(wkavg + (size_t)d * 1024 + k8) = o;
  if (blockIdx.x == 0 && threadIdx.x < 64) {
    float b = 0.f;
#pragma unroll
    for (int h = 0; h < 16; ++h) b += bk[h * 64 + threadIdx.x];
    bkavg[threadIdx.x] = b * 0.0625f;
  }
}

// ------- GEMM: C[M,N] = A[M,1024] * Bm[N,1024]^T (NT, bf16 MFMA) ---------------
// 128x128 tile, BK=64, double-buffered LDS, 2-phase pipeline, chunk-XOR swizzle.
// EPI==0: N=3200. Regions: Q (RoPE), K (RoPE), V (transpose), metric (RoPE+f32).
// EPI==1: O-proj epilogue (bias + f32 store)
#define GEMM_STAGE(BUF, KK)                                                        \
  {                                                                                \
    char* Ab = smem + (BUF) * 32768;                                               \
    char* Bb = Ab + 16384;                                                         \
    _Pragma("unroll") for (int q = 0; q < 4; ++q) {                                \
      int idx = q * 256 + tid;                                                     \
      int row = idx >> 3, c = idx & 7;                                             \
      gload_lds16(A  + (size_t)(m0 + row) * 1024 + (KK) + ((c ^ (row & 7)) << 3),  \
                  Ab + q * 4096 + wid * 1024);                                     \
      gload_lds16(Bm + (size_t)(n0 + row) * 1024 + (KK) + ((c ^ (row & 7)) << 3),  \
                  Bb + q * 4096 + wid * 1024);                                     \
    }                                                                              \
  }

template<int EPI>
__global__ __launch_bounds__(256, 2)
void gemm_kernel(const __bf16* __restrict__ A, const __bf16* __restrict__ Bm, int N,
                 const float* __restrict__ b0, const float* __restrict__ b1,
                 const float* __restrict__ b2, const float* __restrict__ bavg,
                 const int* __restrict__ pos_ids,
                 __bf16* __restrict__ Qr, __bf16* __restrict__ Kr, __bf16* __restrict__ Vtg,
                 float* __restrict__ metric, float* __restrict__ Cout) {
  __shared__ __align__(16) char smem[65536];     // 2 x (As 16K | Bs 16K); vt_s reuse
  const int tid = threadIdx.x;
  const int wid = tid >> 6, lane = tid & 63;
  const int g = lane >> 4, cl = lane & 15;
  const int ntn = N >> 7;
  const int tile = (blockIdx.x & 7) * ((int)gridDim.x >> 3) + (blockIdx.x >> 3);
  const int bm = tile / ntn, bn = tile % ntn;
  const int m0 = bm << 7, n0 = bn << 7;
  const int wr = (wid >> 1) << 6, wc = (wid & 1) << 6;
  const int swz = cl & 7;

  f32x4 acc[4][4] = {};

  GEMM_STAGE(0, 0);
  __syncthreads();                                // tile-0 landed
  int buf = 0;
  for (int t = 0; t < 16; ++t) {
    if (t + 1 < 16) GEMM_STAGE(buf ^ 1, (t + 1) * 64);   // prefetch next K-step
    const __bf16* Abuf = (const __bf16*)(smem + buf * 32768);
    const __bf16* Bbuf = Abuf + 8192;
#pragma unroll
    for (int s = 0; s < 2; ++s) {                 // two K=32 substeps
      bf16x8 fa[4], fb[4];
#pragma unroll
      for (int i = 0; i < 4; ++i)
        fa[i] = *(const bf16x8*)(Abuf + (wr + i * 16 + cl) * 64 + (((s * 4 + g) ^ swz) << 3));
#pragma unroll
      for (int j = 0; j < 4; ++j)
        fb[j] = *(const bf16x8*)(Bbuf + (wc + j * 16 + cl) * 64 + (((s * 4 + g) ^ swz) << 3));
#pragma unroll
      for (int i = 0; i < 4; ++i)
#pragma unroll
        for (int j = 0; j < 4; ++j)
          acc[i][j] = __builtin_amdgcn_mfma_f32_16x16x32_bf16(fa[i], fb[j], acc[i][j], 0, 0, 0);
    }
    __syncthreads();                              // drains prefetch (full compute cover)
    buf ^= 1;
  }

  if constexpr (EPI == 1) {
#pragma unroll
    for (int j = 0; j < 4; ++j) {
      int col = n0 + wc + j * 16 + cl;
      float bv = b0[col];
#pragma unroll
      for (int i = 0; i < 4; ++i)
#pragma unroll
        for (int r = 0; r < 4; ++r) {
          int row = m0 + wr + i * 16 + g * 4 + r;
          Cout[(size_t)row * 1024 + col] = acc[i][j][r] + bv;
        }
    }
  } else if (n0 >= 3072) {
    // ---- metric region (cols 3072-3135 = Wk_avg): RoPE + direct f32 store ----
    if (wc == 0) {
      float invf0 = exp2f(-0.4152410118609203f * (float)(cl));
      float invf1 = exp2f(-0.4152410118609203f * (float)(16 + cl));
#pragma unroll
      for (int i = 0; i < 4; ++i) {
#pragma unroll
        for (int r = 0; r < 4; ++r) {
          int row = m0 + wr + i * 16 + g * 4 + r;
          float pos = (float)pos_ids[row];
#pragma unroll
          for (int j = 0; j < 2; ++j) {
            int dlo = j * 16 + cl;
            float vlo = acc[i][j][r]     + bavg[dlo];
            float vhi = acc[i][j + 2][r] + bavg[dlo + 32];
            float th = pos * (j == 0 ? invf0 : invf1);
            float sn, cs;
            __sincosf(th, &sn, &cs);
            metric[(size_t)row * HDD + dlo]      = vlo * cs - vhi * sn;
            metric[(size_t)row * HDD + dlo + 32] = vhi * cs + vlo * sn;
          }
        }
      }
    }
  } else if (n0 >= 2048) {
    // ---- V region: bias + transpose through LDS -> Vtg[b][h][d][s] ----
    __bf16* vt_s = (__bf16*)smem;                 // [64][136]
    const int b_ = m0 >> 10, s0 = m0 & 1023;
    const int vbase = n0 - 2048;                  // v-col base of this block
#pragma unroll
    for (int phase = 0; phase < 2; ++phase) {
      __syncthreads();                            // vt_s free (main loop / prev phase)
      if ((wid & 1) == phase) {
#pragma unroll
        for (int j = 0; j < 4; ++j) {
          int d = j * 16 + cl;                    // 0..63 within head
          float bv = b2[vbase + wc + d];
#pragma unroll
          for (int i = 0; i < 4; ++i)
#pragma unroll
            for (int r = 0; r < 4; ++r)
              vt_s[d * 136 + wr + i * 16 + g * 4 + r] = (__bf16)(acc[i][j][r] + bv);
        }
      }
      __syncthreads();
      int hh = (vbase >> 6) + phase;
#pragma unroll
      for (int p = 0; p < 4; ++p) {
        int d = p * 16 + (tid >> 4), s8 = (tid & 15) * 8;
        bf16x8 v = *(const bf16x8*)(vt_s + d * 136 + s8);
        *(bf16x8*)(Vtg + ((size_t)(b_ * HH + hh) * HDD + d) * SS + s0 + s8) = v;
      }
    }
  } else {
    // ---- Q/K region: bias + RoPE + scatter (no atomics) ----
    const int cb = n0 + wc;                 // 64-aligned -> exactly one head
    const int region = cb >> 10;            // 0=q 1=k
    const int hcol = (cb & 1023) >> 6;
    const int cir = cb & 1023;
    const float* bias = region == 0 ? b0 : b1;
    __bf16* dst = region == 0 ? Qr : Kr;
    float invf0 = exp2f(-0.4152410118609203f * (float)(cl));
    float invf1 = exp2f(-0.4152410118609203f * (float)(16 + cl));
#pragma unroll
    for (int i = 0; i < 4; ++i) {
#pragma unroll
      for (int r = 0; r < 4; ++r) {
        int row = m0 + wr + i * 16 + g * 4 + r;   // = b*1024 + s
        int b_ = row >> 10, s = row & 1023;
        size_t ob = ((size_t)(b_ * HH + hcol) * SS + s) * HDD;
        float pos = (float)pos_ids[row];
#pragma unroll
        for (int j = 0; j < 2; ++j) {
          int dlo = j * 16 + cl;                       // 0..31
          float vlo = acc[i][j][r]     + bias[cir + dlo];
          float vhi = acc[i][j + 2][r] + bias[cir + dlo + 32];
          float th = pos * (j == 0 ? invf0 : invf1);
          float sn, cs;
          __sincosf(th, &sn, &cs);
          float olo = vlo * cs - vhi * sn;             // rot_half: d<32 -> -q[d+32]
          float ohi = vhi * cs + vlo * sn;             // d>=32 ->  q[d-32]
          dst[ob + dlo]      = (__bf16)olo;
          dst[ob + dlo + 32] = (__bf16)ohi;
        }
      }
    }
  }
}

// ---------------- flash attention: KBLK=128 + counted-vmcnt pipeline ------------
#define ATTN_HALF(KT0, W0, BCUR)                                                   \
  {                                                                                \
    f32x4 sc[4];                                                                   \
    __builtin_amdgcn_s_setprio(1);                                                 \
    _Pragma("unroll") for (int kt = 0; kt < 4; ++kt) {                             \
      int row = (KT0 + kt) * 16 + cl;                                              \
      bf16x8 kb0 = *(const bf16x8*)(&Ks[buf][row][(g ^ swz) * 8]);                 \
      bf16x8 kb1 = *(const bf16x8*)(&Ks[buf][row][((g + 4) ^ swz) * 8]);           \
      f32x4 z = {0.f, 0.f, 0.f, 0.f};                                              \
      z = __builtin_amdgcn_mfma_f32_16x16x32_bf16(kb0, aq0, z, 0, 0, 0);           \
      sc[kt] = __builtin_amdgcn_mfma_f32_16x16x32_bf16(kb1, aq1, z, 0, 0, 0);      \
    }                                                                              \
    __builtin_amdgcn_s_setprio(0);                                                 \
    _Pragma("unroll") for (int kt = 0; kt < 4; ++kt)                               \
      _Pragma("unroll") for (int r = 0; r < 4; ++r)                                \
        sc[kt][r] = sc[kt][r] * 0.125f + BCUR[KT0 + kt][r];                        \
    float mx = fmaxf(fmaxf(fmaxf(sc[0][0], sc[0][1]), fmaxf(sc[0][2], sc[0][3])),  \
                     fmaxf(fmaxf(sc[1][0], sc[1][1]), fmaxf(sc[1][2], sc[1][3]))); \
    mx = fmaxf(mx, fmaxf(fmaxf(fmaxf(sc[2][0], sc[2][1]), fmaxf(sc[2][2], sc[2][3])), \
                         fmaxf(fmaxf(sc[3][0], sc[3][1]), fmaxf(sc[3][2], sc[3][3])))); \
    mx = fmaxf(mx, __shfl_xor(mx, 16, 64));                                        \
    mx = fmaxf(mx, __shfl_xor(mx, 32, 64));                                        \
    if (!__all(mx <= m_l + 8.0f)) {                                                \
      float nm = fmaxf(m_l, mx);                                                   \
      float s_ = __expf(m_l - nm);                                                 \
      m_l = nm; l_l *= s_;                                                         \
      float sb0 = __shfl(s_, 4 * g + 0, 64), sb1 = __shfl(s_, 4 * g + 1, 64);      \
      float sb2 = __shfl(s_, 4 * g + 2, 64), sb3 = __shfl(s_, 4 * g + 3, 64);      \
      _Pragma("unroll") for (int dj = 0; dj < 4; ++dj) {                           \
        o[dj][0] *= sb0; o[dj][1] *= sb1; o[dj][2] *= sb2; o[dj][3] *= sb3;        \
      }                                                                            \
    }                                                                              \
    _Pragma("unroll") for (int kt = 0; kt < 4; ++kt)                               \
      _Pragma("unroll") for (int r = 0; r < 4; ++r)                                \
        sc[kt][r] = __expf(sc[kt][r] - m_l);                                       \
    float rs = ((sc[0][0] + sc[0][1]) + (sc[0][2] + sc[0][3]))                     \
             + ((sc[1][0] + sc[1][1]) + (sc[1][2] + sc[1][3]))                     \
             + ((sc[2][0] + sc[2][1]) + (sc[2][2] + sc[2][3]))                     \
             + ((sc[3][0] + sc[3][1]) + (sc[3][2] + sc[3][3]));                    \
    rs += __shfl_xor(rs, 16, 64);                                                  \
    rs += __shfl_xor(rs, 32, 64);                                                  \
    l_l += rs;                                                                     \
    _Pragma("unroll") for (int w = 0; w < 2; ++w) {                                \
      _Pragma("unroll") for (int k2 = 0; k2 < 2; ++k2) {                           \
        int kt = w * 2 + k2;                                                       \
        bf16x4 pk;                                                                 \
        pk[0] = (__bf16)sc[kt][0]; pk[1] = (__bf16)sc[kt][1];                      \
        pk[2] = (__bf16)sc[kt][2]; pk[3] = (__bf16)sc[kt][3];                      \
        *(bf16x4*)(Pw + cl * 40 + k2 * 16 + 4 * g) = pk;                           \
      }                                                                            \
      bf16x8 pa = *(const bf16x8*)(Pw + cl * 40 + g * 8);                          \
      __builtin_amdgcn_s_setprio(1);                                               \
      _Pragma("unroll") for (int dj = 0; dj < 4; ++dj) {                           \
        int vrow = dj * 16 + cl;                                                   \
        bf16x8 vb = *(const bf16x8*)(&Vt[buf][vrow][((((W0 + w) * 4) + g) ^ swz) * 8]); \
        o[dj] = __builtin_amdgcn_mfma_f32_16x16x32_bf16(pa, vb, o[dj], 0, 0, 0);   \
      }                                                                            \
      __builtin_amdgcn_s_setprio(0);                                               \
    }                                                                              \
  }

#define ATTN_STAGE(NB, KK)                                                         \
  _Pragma("unroll") for (int s = 0; s < 2; ++s) {                                  \
    gload_lds16(Kb + (size_t)((KK) + s * 64 + krow) * 64 + kchk * 8,               \
                (char*)&Ks[NB][s * 64 + 8 * wid][0]);                              \
    gload_lds16(Vb + (size_t)(s * 32 + vrow) * SS + (KK) + vchk * 8,               \
                (char*)&Vt[NB][s * 32 + 4 * wid][0]);                              \
  }

__global__ __launch_bounds__(512, 4)
void attn_kernel(const __bf16* __restrict__ Qr, const __bf16* __restrict__ Kr,
                 const __bf16* __restrict__ Vtg, const float* __restrict__ bias,
                 const int* __restrict__ pad, __bf16* __restrict__ attn_out) {
  __shared__ __align__(16) __bf16 Ks[2][128][64];  // 32 KB [buf][k][d] swizzled
  __shared__ __align__(16) __bf16 Vt[2][64][128];  // 32 KB [buf][d][k] swizzled
  __shared__ __align__(16) __bf16 Plds[8][16][40]; // 10 KB per-wave P window
  const int tid = threadIdx.x;
  const int wid = tid >> 6, lane = tid & 63;
  const int g = lane >> 4, cl = lane & 15;
  const int bh = blockIdx.x & 63, b_ = bh >> 4, h = bh & 15;   // bh-major: XCD = bh%8
  const int q0 = (blockIdx.x >> 6) * 128 + wid * 16;
  const __bf16* Qb = Qr  + ((size_t)bh << 16);
  const __bf16* Kb = Kr  + ((size_t)bh << 16);
  const __bf16* Vb = Vtg + ((size_t)bh << 16);
  const float*  Bb = bias + ((size_t)bh << 20);
  const int* padb = pad + b_ * SS;

  int pm = (lane < 16) ? padb[lane * 64] : 1;
  unsigned long long ball = __ballot(pm == 0);
  const int valid64 = __popcll(ball & 0xFFFFull);
  const int nt = (valid64 + 1) >> 1;
  const int tail = valid64 & 1;

  const int krow = 8 * wid + (lane >> 3);
  const int kchk = (lane & 7) ^ (lane >> 3);
  const int vrow = 4 * wid + (lane >> 4);
  const int vchk = (lane & 15) ^ (vrow & 7);
  const int swz = cl & 7;
  __bf16* Pw = &Plds[wid][0][0];

  bf16x8 aq0 = *(const bf16x8*)(Qb + (size_t)(q0 + cl) * 64 + g * 8);
  bf16x8 aq1 = *(const bf16x8*)(Qb + (size_t)(q0 + cl) * 64 + 32 + g * 8);
  __builtin_amdgcn_sched_barrier(0);

  ATTN_STAGE(0, 0);
  __builtin_amdgcn_sched_barrier(0);
  f32x4 breg[8];
#pragma unroll
  for (int kt = 0; kt < 8; ++kt)
    breg[kt] = *(const f32x4*)(Bb + (size_t)(q0 + cl) * SS + kt * 16 + 4 * g);
  __builtin_amdgcn_sched_barrier(0);

  f32x4 o[4] = {};
  float m_l = -1e30f, l_l = 0.f;

  for (int t = 0; t < nt; ++t) {
    const int buf = t & 1;
    asm volatile("s_waitcnt vmcnt(8)" ::: "memory");
    __builtin_amdgcn_s_barrier();
    __builtin_amdgcn_sched_barrier(0);
    if (t + 1 < nt) {
      ATTN_STAGE(buf ^ 1, (t + 1) * 128);
      __builtin_amdgcn_sched_barrier(0);
    }

    ATTN_HALF(0, 0, breg);

    if (t + 1 < nt) {
      int kk2 = (t + 1) * 128;
#pragma unroll
      for (int kt = 0; kt < 4; ++kt)
        breg[kt] = *(const f32x4*)(Bb + (size_t)(q0 + cl) * SS + kk2 + kt * 16 + 4 * g);
      __builtin_amdgcn_sched_barrier(0);
    }

    if (!(tail && t == nt - 1))
      ATTN_HALF(4, 2, breg);

    if (t + 1 < nt) {
      int kk2 = (t + 1) * 128;
#pragma unroll
      for (int kt = 4; kt < 8; ++kt)
        breg[kt] = *(const f32x4*)(Bb + (size_t)(q0 + cl) * SS + kk2 + kt * 16 + 4 * g);
      __builtin_amdgcn_sched_barrier(0);
    }
  }

  float lb0 = __shfl(l_l, 4 * g + 0, 64), lb1 = __shfl(l_l, 4 * g + 1, 64);
  float lb2 = __shfl(l_l, 4 * g + 2, 64), lb3 = __shfl(l_l, 4 * g + 3, 64);
  float ib0 = 1.f / lb0, ib1 = 1.f / lb1, ib2 = 1.f / lb2, ib3 = 1.f / lb3;
#pragma unroll
  for (int dj = 0; dj < 4; ++dj) {
    int col = h * 64 + dj * 16 + cl;
    attn_out[(size_t)(b_ * SS + q0 + g * 4 + 0) * DD + col] = (__bf16)(o[dj][0] * ib0);
    attn_out[(size_t)(b_ * SS + q0 + g * 4 + 1) * DD + col] = (__bf16)(o[dj][1] * ib1);
    attn_out[(size_t)(b_ * SS + q0 + g * 4 + 2) * DD + col] = (__bf16)(o[dj][2] * ib2);
    attn_out[(size_t)(b_ * SS + q0 + g * 4 + 3) * DD + col] = (__bf16)(o[dj][3] * ib3);
  }
}

// ------------------------------- launcher --------------------------------------
extern "C" void kernel_launch(void* const* d_in, const int* in_sizes, int n_in,
                              void* d_out, int out_size, void* d_ws, size_t ws_size,
                              hipStream_t stream) {
  const float* x  = (const float*)d_in[0];
  const float* ab = (const float*)d_in[1];
  const int* pos  = (const int*)d_in[2];
  const int* pad  = (const int*)d_in[3];
  const float* Wq = (const float*)d_in[4];
  const float* bq = (const float*)d_in[5];
  const float* Wk = (const float*)d_in[6];
  const float* bk = (const float*)d_in[7];
  const float* Wv = (const float*)d_in[8];
  const float* bv = (const float*)d_in[9];
  const float* Wo = (const float*)d_in[10];
  const float* bo = (const float*)d_in[11];
  float* out = (float*)d_out;
  float* metric = out + 4194304;           // [B,S,64] f32

  char* ws = (char*)d_ws;
  __bf16* Qr    = (__bf16*)(ws);                 // [B,H,S,64] bf16, 8 MB
  __bf16* Kr    = (__bf16*)(ws + 8388608);       // [B,H,S,64]
  __bf16* Vtg   = (__bf16*)(ws + 16777216);      // [B,H,64,S]  (pre-transposed V)
  __bf16* xb    = (__bf16*)(ws + 25165824);      // [4096,1024] bf16
  __bf16* wqkv  = (__bf16*)(ws + 33554432);      // [3200,1024] bf16 (rows 3072+ = Wk_avg)
  __bf16* wob   = (__bf16*)(ws + 40108032);      // [1024,1024] bf16
  __bf16* ao    = (__bf16*)(ws + 42205184);      // attn out [4096,1024] bf16
  float*  bkavg = (float*)(ws + 50593792);       // [64] f32

  convert_kernel<<<8192, 256, 0, stream>>>((const float4*)x, (const float4*)Wq,
                                           (const float4*)Wk, (const float4*)Wv,
                                           (const float4*)Wo, (bf16x4*)xb,
                                           (bf16x4*)wqkv, (bf16x4*)wob);
  prep_kernel<<<16, 512, 0, stream>>>(wqkv, bk, wqkv + (size_t)3072 * 1024, bkavg);
  gemm_kernel<0><<<800, 256, 0, stream>>>(xb, wqkv, 3200, bq, bk, bv, bkavg, pos,
                                          Qr, Kr, Vtg, metric, nullptr);
  attn_kernel<<<512, 512, 0, stream>>>(Qr, Kr, Vtg, ab, pad, ao);
  gemm_kernel<1><<<256, 256, 0, stream>>>(ao, wob, 1024, bo, nullptr, nullptr, nullptr,
                                          nullptr, nullptr, nullptr, nullptr, nullptr, out);
}